// Round 5
// baseline (51632.587 us; speedup 1.0000x reference)
//
#include <hip/hip_runtime.h>
#include <stdint.h>

typedef unsigned short ushort_t;
typedef unsigned long long u64;
typedef __attribute__((ext_vector_type(8))) short short8;
typedef __attribute__((ext_vector_type(4))) float f32x4;
typedef __attribute__((ext_vector_type(16))) float f32x16;

#define WS_W0T_HI 0u
#define WS_W0T_LO (2u<<20)
#define WS_WST_HI (4u<<20)
#define WS_WST_LO (12u<<20)
#define WS_ST     (20u<<20)
#define WS_BAR    (26u<<20)

#define SLOT_F 131072     // floats per f32 state slot (256*512)
#define PSTR 520          // LDS panel row stride in elems (16B-aligned rows, low conflict)

// f32 state slots: 0=h, 1=s0, 2=s1, 3=s2, 4=s3, 5=s5

__device__ __forceinline__ ushort_t f2bf(float f) {
  unsigned u = __float_as_uint(f);
  u += 0x7FFFu + ((u >> 16) & 1u);          // RNE to bf16
  return (ushort_t)(u >> 16);
}
__device__ __forceinline__ float bf2f(ushort_t h) {
  return __uint_as_float(((unsigned)h) << 16);
}
__device__ __forceinline__ float sigf(float v) { return 1.f / (1.f + __expf(-v)); }

// 8B uncached (device-coherent) load/store of f32 pairs
__device__ __forceinline__ u64 ald8(const float* p) {
  return __hip_atomic_load((const u64*)p, __ATOMIC_RELAXED, __HIP_MEMORY_SCOPE_AGENT);
}
__device__ __forceinline__ void st_pair(float* slot, int off, float s, int tid) {
  float ns = __shfl_xor(s, 1, 64);
  if (!(tid & 1)) {
    union { float f[2]; u64 q; } u;
    u.f[0] = s; u.f[1] = ns;
    __hip_atomic_store((u64*)(slot + off), u.q, __ATOMIC_RELAXED, __HIP_MEMORY_SCOPE_AGENT);
  }
}

// convert 8 f32 (plain cached loads) -> bf16 hi/lo fragments (stage A x-path)
__device__ __forceinline__ void xcvt(const float* xp, short8& ah, short8& al) {
  f32x4 v0 = *(const f32x4*)xp;
  f32x4 v1 = *(const f32x4*)(xp + 4);
#pragma unroll
  for (int i = 0; i < 4; ++i) {
    ushort_t h0 = f2bf(v0[i]);
    ah[i] = (short)h0; al[i] = (short)f2bf(v0[i] - bf2f(h0));
    ushort_t h1 = f2bf(v1[i]);
    ah[i + 4] = (short)h1; al[i + 4] = (short)f2bf(v1[i] - bf2f(h1));
  }
}

// ---------------- prep: transpose + hi/lo split weights; h0 -> f32 slot0 ----
extern "C" __global__ void prep_kernel(const float* __restrict__ W0,
                                       const float* __restrict__ Ws,
                                       const float* __restrict__ h0,
                                       char* __restrict__ ws) {
  ushort_t* w0h = (ushort_t*)(ws + WS_W0T_HI);
  ushort_t* w0l = (ushort_t*)(ws + WS_W0T_LO);
  ushort_t* wsh = (ushort_t*)(ws + WS_WST_HI);
  ushort_t* wsl = (ushort_t*)(ws + WS_WST_LO);
  float* st0 = (float*)(ws + WS_ST);
  const long N0 = 1048576, N1 = 4194304, N2 = 131072;
  long total = N0 + N1 + N2;
  for (long idx = (long)blockIdx.x * blockDim.x + threadIdx.x; idx < total;
       idx += (long)gridDim.x * blockDim.x) {
    if (idx < N0) {                       // W0T[j][k] from W0[k][j], K=1024
      int k = (int)(idx >> 10), j = (int)(idx & 1023);
      float v = W0[k * 1024 + j];
      ushort_t hi = f2bf(v);
      w0h[j * 1024 + k] = hi;
      w0l[j * 1024 + k] = f2bf(v - bf2f(hi));
    } else if (idx < N0 + N1) {           // WsT[i][j][k] from Ws[i][k][j], K=512
      long r = idx - N0;
      int i = (int)(r >> 19);
      int r2 = (int)(r & 524287);
      int k = r2 >> 10, j = r2 & 1023;
      float v = Ws[(long)i * 524288 + k * 1024 + j];
      ushort_t hi = f2bf(v);
      wsh[(long)i * 524288 + j * 512 + k] = hi;
      wsl[(long)i * 524288 + j * 512 + k] = f2bf(v - bf2f(hi));
    } else {                              // h0 -> slot 0 (f32 copy)
      int e = (int)(idx - N0 - N1);
      st0[e] = h0[e];
    }
  }
}

// -------- 8-WG cross-XCD barrier per row-group (per-WG epoch flags) --------
__device__ __forceinline__ void gbar(unsigned* flags, int rt, int cs, unsigned gen) {
  __syncthreads();   // drains each wave's vmcnt: state stores are coherent-visible
  if (threadIdx.x == 0)
    __hip_atomic_store(flags + (rt * 8 + cs) * 32, gen, __ATOMIC_RELAXED, __HIP_MEMORY_SCOPE_AGENT);
  if (threadIdx.x < 64) {
    const unsigned* f = flags + (rt * 8 + (threadIdx.x & 7)) * 32;
    while (__hip_atomic_load(f, __ATOMIC_RELAXED, __HIP_MEMORY_SCOPE_AGENT) < gen)
      __builtin_amdgcn_s_sleep(2);
  }
  __syncthreads();
  asm volatile("" ::: "memory");
}

// cooperative A-panel load: 32 rows x 512 f32 -> LDS bf16 hi/lo planes.
// 16 independent 8B uncached loads per thread (all in flight), then cvt+ds_write.
__device__ __forceinline__ void load_panel(const float* slot, int r0,
                                           ushort_t* AhB, ushort_t* AlB, int tid) {
  u64 q[16];
#pragma unroll
  for (int ii = 0; ii < 4; ++ii) {
    int c = ii * 512 + tid;
    int row = c >> 6, k8 = (c & 63) << 3;
    const float* src = slot + (r0 + row) * 512 + k8;
#pragma unroll
    for (int j = 0; j < 4; ++j) q[ii * 4 + j] = ald8(src + 2 * j);
  }
#pragma unroll
  for (int ii = 0; ii < 4; ++ii) {
    int c = ii * 512 + tid;
    int row = c >> 6, k8 = (c & 63) << 3;
    short8 hh, ll;
#pragma unroll
    for (int j = 0; j < 4; ++j) {
      union { u64 q; float f[2]; } u; u.q = q[ii * 4 + j];
#pragma unroll
      for (int m = 0; m < 2; ++m) {
        ushort_t hb = f2bf(u.f[m]);
        hh[2 * j + m] = (short)hb;
        ll[2 * j + m] = (short)f2bf(u.f[m] - bf2f(hb));
      }
    }
    *(short8*)(AhB + row * PSTR + k8) = hh;
    *(short8*)(AlB + row * PSTR + k8) = ll;
  }
}

__device__ __forceinline__ f32x16 mfma3(short8 ah, short8 al, short8 bh, short8 bl, f32x16 acc) {
  acc = __builtin_amdgcn_mfma_f32_32x32x16_bf16(ah, bh, acc, 0, 0, 0);
  acc = __builtin_amdgcn_mfma_f32_32x32x16_bf16(ah, bl, acc, 0, 0, 0);
  acc = __builtin_amdgcn_mfma_f32_32x32x16_bf16(al, bh, acc, 0, 0, 0);
  return acc;
}

// K=512 stage: A-frags from LDS panel, NP weight matrices, kh halves K
template<int NP>
__device__ __forceinline__ void mm_unit(const ushort_t* AhB, const ushort_t* AlB,
                                        const ushort_t* const (&bh)[NP],
                                        const ushort_t* const (&bl)[NP],
                                        int b512, int kh, int lr, int lk8,
                                        f32x16 (&acc)[NP]) {
  const int kb = kh * 256 + lk8;
#pragma unroll
  for (int i = 0; i < 16; ++i) {
    int kq = kb + i * 16;
    short8 a_h = *(const short8*)(AhB + lr * PSTR + kq);
    short8 a_l = *(const short8*)(AlB + lr * PSTR + kq);
#pragma unroll
    for (int p = 0; p < NP; ++p) {
      short8 b_h = *(const short8*)(bh[p] + b512 + kq);
      short8 b_l = *(const short8*)(bl[p] + b512 + kq);
      acc[p] = mfma3(a_h, a_l, b_h, b_l, acc[p]);
    }
  }
}

__device__ __forceinline__ void wr_pp(float* pp, const f32x16& a, int kh, int ct, int lane) {
  int col = lane & 31, h5 = lane >> 5;
  float* base = pp + ((kh * 4 + ct) * 32) * 33 + col;
#pragma unroll
  for (int r = 0; r < 16; ++r) {
    int row = (r & 3) + 8 * (r >> 2) + 4 * h5;   // verified 32x32 C/D layout
    base[row * 33] = a[r];
  }
}

__device__ __forceinline__ void getch(const float* pp, int q, int row, int cv,
                                      float& c, float& h) {
  int b0 = ((0 * 4 + q) * 32 + row) * 33;
  int b1 = ((1 * 4 + q) * 32 + row) * 33;
  c = pp[b0 + cv] + pp[b1 + cv];
  h = pp[b0 + cv + 16] + pp[b1 + cv + 16];
}

// ---------------- main persistent cooperative kernel -----------------------
extern "C" __global__ void __launch_bounds__(512, 1)
rnn_main(const float* __restrict__ x, float* __restrict__ out, char* __restrict__ ws) {
  __shared__ ushort_t Ah[32 * PSTR];      // 33 KB  A-panel hi
  __shared__ ushort_t Al[32 * PSTR];      // 33 KB  A-panel lo
  __shared__ float pp[2 * 4 * 32 * 33];   // 33 KB  kh-split partials

  float* st = (float*)(ws + WS_ST);
  unsigned* flags = (unsigned*)(ws + WS_BAR);
  const ushort_t* w0h = (const ushort_t*)(ws + WS_W0T_HI);
  const ushort_t* w0l = (const ushort_t*)(ws + WS_W0T_LO);
  const ushort_t* wsh = (const ushort_t*)(ws + WS_WST_HI);
  const ushort_t* wsl = (const ushort_t*)(ws + WS_WST_LO);

  const int tid = threadIdx.x;
  const int wg = blockIdx.x;
  const int cs = wg & 7;                  // column-slice, pinned to XCD (wg%8)
  const int rt = wg >> 3;                 // row group 0..7
  const int r0 = rt * 32;
  const int vc0 = cs * 64;                // 64 virtual cols (gate pairs) per WG

  const int w = tid >> 6, lane = tid & 63;
  const int ct = w >> 1, kh = w & 1;      // 4 col-tiles x 2 K-halves
  const int lr = lane & 31, lk8 = (lane >> 5) * 8;
  const int jc = vc0 + ct * 16 + (lr & 15) + (lr >> 4) * 512;
  const int b512 = jc * 512, b1024 = jc * 1024;

  const int erow = tid >> 4, ecv = tid & 15;   // epilogue element coords

  float sumreg[4] = {0.f, 0.f, 0.f, 0.f};
  unsigned gen = 1;

  for (int t = 0; t < 400; ++t) {
    // ================= stage A: s0 = h + sig(c)*(tanh(h) - h), A=[x|h] =====
    load_panel(st + 0 * SLOT_F, r0, Ah, Al, tid);
    __syncthreads();
    {
      f32x16 acc[1] = {};
      if (kh == 0) {                      // K 0..512 = x (plain cached f32)
        const float* xr = x + (size_t)t * 131072 + (size_t)(r0 + lr) * 512;
#pragma unroll
        for (int i = 0; i < 32; ++i) {
          int kq = i * 16 + lk8;
          short8 a_h, a_l;
          xcvt(xr + kq, a_h, a_l);
          short8 b_h = *(const short8*)(w0h + b1024 + kq);
          short8 b_l = *(const short8*)(w0l + b1024 + kq);
          acc[0] = mfma3(a_h, a_l, b_h, b_l, acc[0]);
        }
      } else {                            // K 512..1024 = h (LDS panel)
#pragma unroll
        for (int i = 0; i < 32; ++i) {
          int kp = i * 16 + lk8;
          short8 a_h = *(const short8*)(Ah + lr * PSTR + kp);
          short8 a_l = *(const short8*)(Al + lr * PSTR + kp);
          int kq = 512 + kp;
          short8 b_h = *(const short8*)(w0h + b1024 + kq);
          short8 b_l = *(const short8*)(w0l + b1024 + kq);
          acc[0] = mfma3(a_h, a_l, b_h, b_l, acc[0]);
        }
      }
      wr_pp(pp, acc[0], kh, ct, lane);
    }
    __syncthreads();
#pragma unroll
    for (int q = 0; q < 4; ++q) {
      float c, hh; getch(pp, q, erow, ecv, c, hh);
      int vg = vc0 + q * 16 + ecv;
      float sp = bf2f(Ah[erow * PSTR + vg]) + bf2f(Al[erow * PSTR + vg]);
      float s = sp + sigf(c) * (tanhf(hh) - sp);
      st_pair(st + 1 * SLOT_F, (r0 + erow) * 512 + vg, s, tid);
    }
    gbar(flags, rt, cs, gen); ++gen;

    // ================= stage B: s1 = f(s0, tanh, Ws[0]) ====================
    load_panel(st + 1 * SLOT_F, r0, Ah, Al, tid);
    __syncthreads();
    {
      f32x16 acc[1] = {};
      const ushort_t* bh[1] = {wsh + 0 * 524288};
      const ushort_t* bl[1] = {wsl + 0 * 524288};
      mm_unit<1>(Ah, Al, bh, bl, b512, kh, lr, lk8, acc);
      wr_pp(pp, acc[0], kh, ct, lane);
    }
    __syncthreads();
#pragma unroll
    for (int q = 0; q < 4; ++q) {
      float c, hh; getch(pp, q, erow, ecv, c, hh);
      int vg = vc0 + q * 16 + ecv;
      float sp = bf2f(Ah[erow * PSTR + vg]) + bf2f(Al[erow * PSTR + vg]);
      float s = sp + sigf(c) * (tanhf(hh) - sp);
      sumreg[q] += s;
      st_pair(st + 2 * SLOT_F, (r0 + erow) * 512 + vg, s, tid);
    }
    gbar(flags, rt, cs, gen); ++gen;

    // ====== stage C: s2(relu,Ws[1]) s3(relu,Ws[2]) s4(ident,Ws[3]) from s1 =
    load_panel(st + 2 * SLOT_F, r0, Ah, Al, tid);
    __syncthreads();
    {
      f32x16 acc[3] = {};
      const ushort_t* bh[3] = {wsh + 1 * 524288, wsh + 2 * 524288, wsh + 3 * 524288};
      const ushort_t* bl[3] = {wsl + 1 * 524288, wsl + 2 * 524288, wsl + 3 * 524288};
      mm_unit<3>(Ah, Al, bh, bl, b512, kh, lr, lk8, acc);
      // p = 0: s2 (relu) -> slot3
      wr_pp(pp, acc[0], kh, ct, lane);
      __syncthreads();
#pragma unroll
      for (int q = 0; q < 4; ++q) {
        float c, hh; getch(pp, q, erow, ecv, c, hh);
        int vg = vc0 + q * 16 + ecv;
        float sp = bf2f(Ah[erow * PSTR + vg]) + bf2f(Al[erow * PSTR + vg]);
        float s = sp + sigf(c) * (fmaxf(hh, 0.f) - sp);
        sumreg[q] += s;
        st_pair(st + 3 * SLOT_F, (r0 + erow) * 512 + vg, s, tid);
      }
      __syncthreads();
      // p = 1: s3 (relu) -> slot4
      wr_pp(pp, acc[1], kh, ct, lane);
      __syncthreads();
#pragma unroll
      for (int q = 0; q < 4; ++q) {
        float c, hh; getch(pp, q, erow, ecv, c, hh);
        int vg = vc0 + q * 16 + ecv;
        float sp = bf2f(Ah[erow * PSTR + vg]) + bf2f(Al[erow * PSTR + vg]);
        float s = sp + sigf(c) * (fmaxf(hh, 0.f) - sp);
        sumreg[q] += s;
        st_pair(st + 4 * SLOT_F, (r0 + erow) * 512 + vg, s, tid);
      }
      __syncthreads();
      // p = 2: s4 (identity), concat-only (no store)
      wr_pp(pp, acc[2], kh, ct, lane);
      __syncthreads();
#pragma unroll
      for (int q = 0; q < 4; ++q) {
        float c, hh; getch(pp, q, erow, ecv, c, hh);
        int vg = vc0 + q * 16 + ecv;
        float sp = bf2f(Ah[erow * PSTR + vg]) + bf2f(Al[erow * PSTR + vg]);
        sumreg[q] += sp + sigf(c) * (hh - sp);
      }
    }
    gbar(flags, rt, cs, gen); ++gen;

    // ================= stage D1: s5 = f(s2, tanh, Ws[4]) -> slot5 ==========
    load_panel(st + 3 * SLOT_F, r0, Ah, Al, tid);
    __syncthreads();
    {
      f32x16 acc[1] = {};
      const ushort_t* bh[1] = {wsh + 4 * 524288};
      const ushort_t* bl[1] = {wsl + 4 * 524288};
      mm_unit<1>(Ah, Al, bh, bl, b512, kh, lr, lk8, acc);
      wr_pp(pp, acc[0], kh, ct, lane);
    }
    __syncthreads();
#pragma unroll
    for (int q = 0; q < 4; ++q) {
      float c, hh; getch(pp, q, erow, ecv, c, hh);
      int vg = vc0 + q * 16 + ecv;
      float sp = bf2f(Ah[erow * PSTR + vg]) + bf2f(Al[erow * PSTR + vg]);
      float s = sp + sigf(c) * (tanhf(hh) - sp);
      sumreg[q] += s;
      st_pair(st + 5 * SLOT_F, (r0 + erow) * 512 + vg, s, tid);
    }
    __syncthreads();                      // panel reads done before D2 reload

    // ================= stage D2: s7 = f(s3, tanh, Ws[6]), concat-only ======
    load_panel(st + 4 * SLOT_F, r0, Ah, Al, tid);
    __syncthreads();
    {
      f32x16 acc[1] = {};
      const ushort_t* bh[1] = {wsh + 6 * 524288};
      const ushort_t* bl[1] = {wsl + 6 * 524288};
      mm_unit<1>(Ah, Al, bh, bl, b512, kh, lr, lk8, acc);
      wr_pp(pp, acc[0], kh, ct, lane);
    }
    __syncthreads();
#pragma unroll
    for (int q = 0; q < 4; ++q) {
      float c, hh; getch(pp, q, erow, ecv, c, hh);
      int vg = vc0 + q * 16 + ecv;
      float sp = bf2f(Ah[erow * PSTR + vg]) + bf2f(Al[erow * PSTR + vg]);
      sumreg[q] += sp + sigf(c) * (tanhf(hh) - sp);
    }
    gbar(flags, rt, cs, gen); ++gen;      // covers D1's s5 stores too

    // ====== stage E: s6(sigmoid,Ws[5]) s8(relu,Ws[7]) from s5; mean; h =====
    load_panel(st + 5 * SLOT_F, r0, Ah, Al, tid);
    __syncthreads();
    {
      f32x16 acc[2] = {};
      const ushort_t* bh[2] = {wsh + 5 * 524288, wsh + 7 * 524288};
      const ushort_t* bl[2] = {wsl + 5 * 524288, wsl + 7 * 524288};
      mm_unit<2>(Ah, Al, bh, bl, b512, kh, lr, lk8, acc);
      // p = 0: s6 (sigmoid), concat-only
      wr_pp(pp, acc[0], kh, ct, lane);
      __syncthreads();
#pragma unroll
      for (int q = 0; q < 4; ++q) {
        float c, hh; getch(pp, q, erow, ecv, c, hh);
        int vg = vc0 + q * 16 + ecv;
        float sp = bf2f(Ah[erow * PSTR + vg]) + bf2f(Al[erow * PSTR + vg]);
        sumreg[q] += sp + sigf(c) * (sigf(hh) - sp);
      }
      __syncthreads();
      // p = 1: s8 (relu), concat-only; then mean -> out + h
      wr_pp(pp, acc[1], kh, ct, lane);
      __syncthreads();
#pragma unroll
      for (int q = 0; q < 4; ++q) {
        float c, hh; getch(pp, q, erow, ecv, c, hh);
        int vg = vc0 + q * 16 + ecv;
        float sp = bf2f(Ah[erow * PSTR + vg]) + bf2f(Al[erow * PSTR + vg]);
        sumreg[q] += sp + sigf(c) * (fmaxf(hh, 0.f) - sp);
        float hn = sumreg[q] * 0.125f;
        int eo = (r0 + erow) * 512 + vg;
        out[(size_t)t * 131072 + eo] = hn;
        if (t == 399) out[(size_t)400 * 131072 + eo] = hn;
        st_pair(st + 0 * SLOT_F, eo, hn, tid);
        sumreg[q] = 0.f;
      }
    }
    gbar(flags, rt, cs, gen); ++gen;
  }
}

// ---------------- host launch ----------------------------------------------
extern "C" void kernel_launch(void* const* d_in, const int* in_sizes, int n_in,
                              void* d_out, int out_size, void* d_ws, size_t ws_size,
                              hipStream_t stream) {
  const float* x  = (const float*)d_in[0];
  const float* h0 = (const float*)d_in[1];
  const float* W0 = (const float*)d_in[2];
  const float* Ws = (const float*)d_in[3];
  float* out = (float*)d_out;
  char* ws = (char*)d_ws;

  (void)in_sizes; (void)n_in; (void)out_size; (void)ws_size;

  (void)hipMemsetAsync(ws + WS_BAR, 0, 16384, stream);
  hipLaunchKernelGGL(prep_kernel, dim3(2048), dim3(256), 0, stream, W0, Ws, h0, ws);

  void* args[3] = {(void*)&x, (void*)&out, (void*)&ws};
  (void)hipLaunchCooperativeKernel((void*)rnn_main, dim3(64), dim3(512), args, 0, stream);
}

// Round 6
// 17774.533 us; speedup vs baseline: 2.9049x; 2.9049x over previous
//
#include <hip/hip_runtime.h>
#include <stdint.h>

typedef unsigned short ushort_t;
typedef unsigned long long u64;
typedef __attribute__((ext_vector_type(8))) short short8;
typedef __attribute__((ext_vector_type(4))) float f32x4;
typedef __attribute__((ext_vector_type(4))) unsigned int u32x4;
typedef __attribute__((ext_vector_type(16))) float f32x16;

#define WS_W0T_HI 0u
#define WS_W0T_LO (2u<<20)
#define WS_WST_HI (4u<<20)
#define WS_WST_LO (12u<<20)
#define WS_ST     (20u<<20)
#define WS_BAR    (26u<<20)

#define SLOT_ELEMS 262144   // per state slot (hi plane + lo plane), elements
#define PLANE 131072        // 256*512
#define PSTR 536            // LDS panel row stride (shorts): 1072B -> 4-way max conflict

// state slots (bf16 hi/lo planes): 0=h, 1=s0, 2=s1, 3=s2, 4=s3, 5=s5

__device__ __forceinline__ ushort_t f2bf(float f) {
  unsigned u = __float_as_uint(f);
  u += 0x7FFFu + ((u >> 16) & 1u);          // RNE to bf16
  return (ushort_t)(u >> 16);
}
__device__ __forceinline__ float bf2f(ushort_t h) {
  return __uint_as_float(((unsigned)h) << 16);
}
__device__ __forceinline__ float sigf(float v) { return 1.f / (1.f + __expf(-v)); }

// 16B uncached load (bypass L1+L2, fresh at L3) — same path as agent-relaxed atomics
__device__ __forceinline__ u32x4 uld16(const void* p) {
  u32x4 r;
  asm volatile("global_load_dwordx4 %0, %1, off sc0 sc1" : "=v"(r) : "v"(p));
  return r;
}

// paired-column state store (uncached 4B words) — unchanged from round 3
__device__ __forceinline__ void st_state(ushort_t* slot, int eo, float s, int tid) {
  ushort_t hi = f2bf(s);
  ushort_t lo = f2bf(s - bf2f(hi));
  unsigned nh = __shfl_xor((unsigned)hi, 1, 64);
  unsigned nl = __shfl_xor((unsigned)lo, 1, 64);
  if (!(tid & 1)) {
    unsigned wh = (unsigned)hi | (nh << 16);
    unsigned wl = (unsigned)lo | (nl << 16);
    __hip_atomic_store((unsigned*)(slot + eo), wh, __ATOMIC_RELAXED, __HIP_MEMORY_SCOPE_AGENT);
    __hip_atomic_store((unsigned*)(slot + PLANE + eo), wl, __ATOMIC_RELAXED, __HIP_MEMORY_SCOPE_AGENT);
  }
}

// convert 8 f32 (plain cached loads) -> bf16 hi/lo fragments (stage A x-path)
__device__ __forceinline__ void xcvt(const float* xp, short8& ah, short8& al) {
  f32x4 v0 = *(const f32x4*)xp;
  f32x4 v1 = *(const f32x4*)(xp + 4);
#pragma unroll
  for (int i = 0; i < 4; ++i) {
    ushort_t h0 = f2bf(v0[i]);
    ah[i] = (short)h0; al[i] = (short)f2bf(v0[i] - bf2f(h0));
    ushort_t h1 = f2bf(v1[i]);
    ah[i + 4] = (short)h1; al[i + 4] = (short)f2bf(v1[i] - bf2f(h1));
  }
}

// ---------------- prep: transpose + hi/lo split weights; convert h0 ---------
extern "C" __global__ void prep_kernel(const float* __restrict__ W0,
                                       const float* __restrict__ Ws,
                                       const float* __restrict__ h0,
                                       char* __restrict__ ws) {
  ushort_t* w0h = (ushort_t*)(ws + WS_W0T_HI);
  ushort_t* w0l = (ushort_t*)(ws + WS_W0T_LO);
  ushort_t* wsh = (ushort_t*)(ws + WS_WST_HI);
  ushort_t* wsl = (ushort_t*)(ws + WS_WST_LO);
  ushort_t* st  = (ushort_t*)(ws + WS_ST);
  const long N0 = 1048576, N1 = 4194304, N2 = 131072;
  long total = N0 + N1 + N2;
  for (long idx = (long)blockIdx.x * blockDim.x + threadIdx.x; idx < total;
       idx += (long)gridDim.x * blockDim.x) {
    if (idx < N0) {                       // W0T[j][k] from W0[k][j], K=1024
      int k = (int)(idx >> 10), j = (int)(idx & 1023);
      float v = W0[k * 1024 + j];
      ushort_t hi = f2bf(v);
      w0h[j * 1024 + k] = hi;
      w0l[j * 1024 + k] = f2bf(v - bf2f(hi));
    } else if (idx < N0 + N1) {           // WsT[i][j][k] from Ws[i][k][j], K=512
      long r = idx - N0;
      int i = (int)(r >> 19);
      int r2 = (int)(r & 524287);
      int k = r2 >> 10, j = r2 & 1023;
      float v = Ws[(long)i * 524288 + k * 1024 + j];
      ushort_t hi = f2bf(v);
      wsh[(long)i * 524288 + j * 512 + k] = hi;
      wsl[(long)i * 524288 + j * 512 + k] = f2bf(v - bf2f(hi));
    } else {                              // h0 -> slot 0
      int e = (int)(idx - N0 - N1);
      float v = h0[e];
      ushort_t hi = f2bf(v);
      st[0 * SLOT_ELEMS + e] = hi;
      st[0 * SLOT_ELEMS + PLANE + e] = f2bf(v - bf2f(hi));
    }
  }
}

// ---- producer-flag sync: set after this WG's stores are drained -----------
__device__ __forceinline__ void set_flag(unsigned* flags, int g, int pt, unsigned gen) {
  __syncthreads();   // per-wave vmcnt(0) drain: uncached stores at coherence point
  if (threadIdx.x == 0)
    __hip_atomic_store(flags + (g * 32 + pt) * 16, gen, __ATOMIC_RELAXED, __HIP_MEMORY_SCOPE_AGENT);
}

// ---- panel load: poll this thread's 2 producers, then bulk 16B uncached ----
// copies 32x512 bf16 hi/lo panel (64KB) into LDS; 8 loads/thread in flight.
__device__ __forceinline__ void panel_load(const ushort_t* slot, int r0,
                                           ushort_t* Ah, ushort_t* Al,
                                           const unsigned* flags, int g, unsigned G,
                                           int tid) {
  const int row = tid >> 4, c0 = (tid & 15) * 32;
  const int p0 = (tid & 15) * 2;          // producers of cols [c0, c0+32)
  const unsigned* f0 = flags + (g * 32 + p0) * 16;
  const unsigned* f1 = flags + (g * 32 + p0 + 1) * 16;
  while (__hip_atomic_load(f0, __ATOMIC_RELAXED, __HIP_MEMORY_SCOPE_AGENT) < G)
    __builtin_amdgcn_s_sleep(2);
  while (__hip_atomic_load(f1, __ATOMIC_RELAXED, __HIP_MEMORY_SCOPE_AGENT) < G)
    __builtin_amdgcn_s_sleep(2);
  const ushort_t* srch = slot + (r0 + row) * 512 + c0;
  u32x4 v[8];
#pragma unroll
  for (int j = 0; j < 4; ++j) v[j] = uld16(srch + j * 8);
#pragma unroll
  for (int j = 0; j < 4; ++j) v[4 + j] = uld16(srch + PLANE + j * 8);
  asm volatile("s_waitcnt vmcnt(0)" ::: "memory");
  __builtin_amdgcn_sched_barrier(0);      // rule #18: pin consumers after waitcnt
#pragma unroll
  for (int j = 0; j < 4; ++j) {
    *(u32x4*)(Ah + row * PSTR + c0 + j * 8) = v[j];
    *(u32x4*)(Al + row * PSTR + c0 + j * 8) = v[4 + j];
  }
}

__device__ __forceinline__ f32x16 mfma3(short8 ah, short8 al, short8 bh, short8 bl, f32x16 acc) {
  acc = __builtin_amdgcn_mfma_f32_32x32x16_bf16(ah, bh, acc, 0, 0, 0);
  acc = __builtin_amdgcn_mfma_f32_32x32x16_bf16(ah, bl, acc, 0, 0, 0);
  acc = __builtin_amdgcn_mfma_f32_32x32x16_bf16(al, bh, acc, 0, 0, 0);
  return acc;
}

// matmul vs NP weight matrices; A-frags from LDS panel (XA: first 512 K from x)
template<int NP, int NBLK, bool XA>
__device__ __forceinline__ void mm_lds(const ushort_t* Ah, const ushort_t* Al,
                                       const float* xrow,
                                       const ushort_t* const (&bh)[NP],
                                       const ushort_t* const (&bl)[NP],
                                       int boff, int kw, int lr,
                                       f32x16 (&acc)[NP]) {
#pragma unroll
  for (int j = 0; j < NBLK; ++j) {
    int kq = j * 128 + kw;
    short8 a_h, a_l;
    if (XA && j < 4) {
      xcvt(xrow + kq, a_h, a_l);
    } else {
      int kp = XA ? (kq - 512) : kq;
      a_h = *(const short8*)(Ah + lr * PSTR + kp);
      a_l = *(const short8*)(Al + lr * PSTR + kp);
    }
#pragma unroll
    for (int p = 0; p < NP; ++p) {
      short8 b_h = *(const short8*)(bh[p] + boff + kq);
      short8 b_l = *(const short8*)(bl[p] + boff + kq);
      acc[p] = mfma3(a_h, a_l, b_h, b_l, acc[p]);
    }
  }
}

__device__ __forceinline__ void wr_pp1(float* pp, const f32x16& a, int w, int lane) {
  int col = lane & 31, h5 = lane >> 5;
  float* base = pp + w * 1056 + col;
#pragma unroll
  for (int r = 0; r < 16; ++r) {
    int row = (r & 3) + 8 * (r >> 2) + 4 * h5;   // verified 32x32 C/D layout
    base[row * 33] = a[r];
  }
}
__device__ __forceinline__ void rd_pp1(const float* pp, int row, int cp,
                                       float& c, float& h) {
  float cs = 0.f, hs = 0.f;
#pragma unroll
  for (int w = 0; w < 8; ++w) {
    cs += pp[w * 1056 + row * 33 + cp];
    hs += pp[w * 1056 + row * 33 + cp + 16];
  }
  c = cs; h = hs;
}

// ---------------- main persistent cooperative kernel -----------------------
extern "C" __global__ void __launch_bounds__(512, 1)
rnn_main(const float* __restrict__ x, float* __restrict__ out, char* __restrict__ ws) {
  __shared__ ushort_t Ah[32 * PSTR];      // 34.3 KB panel hi
  __shared__ ushort_t Al[32 * PSTR];      // 34.3 KB panel lo
  __shared__ float pp[8 * 1056];          // 33.8 KB wave partials (one matrix at a time)

  ushort_t* stg = (ushort_t*)(ws + WS_ST);
  unsigned* flags = (unsigned*)(ws + WS_BAR);
  const ushort_t* w0h = (const ushort_t*)(ws + WS_W0T_HI);
  const ushort_t* w0l = (const ushort_t*)(ws + WS_W0T_LO);
  const ushort_t* wsh = (const ushort_t*)(ws + WS_WST_HI);
  const ushort_t* wsl = (const ushort_t*)(ws + WS_WST_LO);

  const int tid = threadIdx.x;
  const int wg = blockIdx.x;
  const int rt = wg >> 5, pt = wg & 31;   // 8 row-groups x 32 col-WGs; XCD=pt%8 (perf)
  const int g = rt, r0 = rt * 32;
  const int w = tid >> 6, lane = tid & 63;
  const int kw = w * 16 + (lane >> 5) * 8;
  const int lr = lane & 31;
  const int jc = pt * 16 + (lr & 15) + (lr >> 4) * 512;  // weight col for B-frags
  const int b512 = jc * 512, b1024 = jc * 1024;
  const int erow = tid >> 4, ecp = tid & 15;
  const int scol = pt * 16 + ecp;
  const int eo = (r0 + erow) * 512 + scol;
  const int spo = erow * PSTR + scol;

  float sumreg = 0.f;

  for (int t = 0; t < 400; ++t) {
    const unsigned base = 5u * (unsigned)t;
    const float* xrow = x + (size_t)t * 131072 + (size_t)(r0 + lr) * 512;

    // ---- stage A: s0 = h + sig(c)*(tanh(h) - h), A=[x|h], W0 (K=1024) -----
    panel_load(stg + 0 * SLOT_ELEMS, r0, Ah, Al, flags, g, base, tid);
    __syncthreads();
    {
      f32x16 acc[1] = {};
      const ushort_t* bh[1] = {w0h};
      const ushort_t* bl[1] = {w0l};
      mm_lds<1, 8, true>(Ah, Al, xrow, bh, bl, b1024, kw, lr, acc);
      __syncthreads();
      wr_pp1(pp, acc[0], w, lane);
      __syncthreads();
      float c, hh; rd_pp1(pp, erow, ecp, c, hh);
      float sp = bf2f(Ah[spo]) + bf2f(Al[spo]);
      float s = sp + sigf(c) * (tanhf(hh) - sp);
      st_state(stg + 1 * SLOT_ELEMS, eo, s, tid);
    }
    set_flag(flags, g, pt, base + 1);

    // ---- stage B: s1 = f(s0, tanh, Ws[0]) ---------------------------------
    panel_load(stg + 1 * SLOT_ELEMS, r0, Ah, Al, flags, g, base + 1, tid);
    __syncthreads();
    {
      f32x16 acc[1] = {};
      const ushort_t* bh[1] = {wsh + 0 * 524288};
      const ushort_t* bl[1] = {wsl + 0 * 524288};
      mm_lds<1, 4, false>(Ah, Al, nullptr, bh, bl, b512, kw, lr, acc);
      __syncthreads();
      wr_pp1(pp, acc[0], w, lane);
      __syncthreads();
      float c, hh; rd_pp1(pp, erow, ecp, c, hh);
      float sp = bf2f(Ah[spo]) + bf2f(Al[spo]);
      float s = sp + sigf(c) * (tanhf(hh) - sp);
      sumreg += s;
      st_state(stg + 2 * SLOT_ELEMS, eo, s, tid);
    }
    set_flag(flags, g, pt, base + 2);

    // ---- stage C: s2(relu) s3(relu) s4(ident) from s1, Ws[1..3] -----------
    panel_load(stg + 2 * SLOT_ELEMS, r0, Ah, Al, flags, g, base + 2, tid);
    __syncthreads();
    {
      f32x16 acc[3] = {};
      const ushort_t* bh[3] = {wsh + 1 * 524288, wsh + 2 * 524288, wsh + 3 * 524288};
      const ushort_t* bl[3] = {wsl + 1 * 524288, wsl + 2 * 524288, wsl + 3 * 524288};
      mm_lds<3, 4, false>(Ah, Al, nullptr, bh, bl, b512, kw, lr, acc);
      float sp;
      __syncthreads();
      wr_pp1(pp, acc[0], w, lane);        // s2 -> slot3
      __syncthreads();
      {
        float c, hh; rd_pp1(pp, erow, ecp, c, hh);
        sp = bf2f(Ah[spo]) + bf2f(Al[spo]);
        float s = sp + sigf(c) * (fmaxf(hh, 0.f) - sp);
        sumreg += s;
        st_state(stg + 3 * SLOT_ELEMS, eo, s, tid);
      }
      __syncthreads();
      wr_pp1(pp, acc[1], w, lane);        // s3 -> slot4
      __syncthreads();
      {
        float c, hh; rd_pp1(pp, erow, ecp, c, hh);
        float s = sp + sigf(c) * (fmaxf(hh, 0.f) - sp);
        sumreg += s;
        st_state(stg + 4 * SLOT_ELEMS, eo, s, tid);
      }
      set_flag(flags, g, pt, base + 3);   // early: D only needs s2/s3
      wr_pp1(pp, acc[2], w, lane);        // s4: concat-only
      __syncthreads();
      {
        float c, hh; rd_pp1(pp, erow, ecp, c, hh);
        sumreg += sp + sigf(c) * (hh - sp);
      }
    }

    // ---- stage D1: s5 = f(s2, tanh, Ws[4]) -> slot5 -----------------------
    __syncthreads();                      // panel reads (sp) done before reload
    panel_load(stg + 3 * SLOT_ELEMS, r0, Ah, Al, flags, g, base + 3, tid);
    __syncthreads();
    {
      f32x16 acc[1] = {};
      const ushort_t* bh[1] = {wsh + 4 * 524288};
      const ushort_t* bl[1] = {wsl + 4 * 524288};
      mm_lds<1, 4, false>(Ah, Al, nullptr, bh, bl, b512, kw, lr, acc);
      __syncthreads();
      wr_pp1(pp, acc[0], w, lane);
      __syncthreads();
      float c, hh; rd_pp1(pp, erow, ecp, c, hh);
      float sp = bf2f(Ah[spo]) + bf2f(Al[spo]);
      float s = sp + sigf(c) * (tanhf(hh) - sp);
      sumreg += s;
      st_state(stg + 5 * SLOT_ELEMS, eo, s, tid);
    }
    set_flag(flags, g, pt, base + 4);

    // ---- stage D2: s7 = f(s3, tanh, Ws[6]), concat-only -------------------
    panel_load(stg + 4 * SLOT_ELEMS, r0, Ah, Al, flags, g, base + 3, tid);
    __syncthreads();
    {
      f32x16 acc[1] = {};
      const ushort_t* bh[1] = {wsh + 6 * 524288};
      const ushort_t* bl[1] = {wsl + 6 * 524288};
      mm_lds<1, 4, false>(Ah, Al, nullptr, bh, bl, b512, kw, lr, acc);
      __syncthreads();
      wr_pp1(pp, acc[0], w, lane);
      __syncthreads();
      float c, hh; rd_pp1(pp, erow, ecp, c, hh);
      float sp = bf2f(Ah[spo]) + bf2f(Al[spo]);
      sumreg += sp + sigf(c) * (tanhf(hh) - sp);
    }

    // ---- stage E: s6(sigmoid,Ws[5]) s8(relu,Ws[7]) from s5; mean; h -------
    __syncthreads();
    panel_load(stg + 5 * SLOT_ELEMS, r0, Ah, Al, flags, g, base + 4, tid);
    __syncthreads();
    {
      f32x16 acc[2] = {};
      const ushort_t* bh[2] = {wsh + 5 * 524288, wsh + 7 * 524288};
      const ushort_t* bl[2] = {wsl + 5 * 524288, wsl + 7 * 524288};
      mm_lds<2, 4, false>(Ah, Al, nullptr, bh, bl, b512, kw, lr, acc);
      __syncthreads();
      wr_pp1(pp, acc[0], w, lane);        // s6
      __syncthreads();
      float sp = bf2f(Ah[spo]) + bf2f(Al[spo]);
      {
        float c, hh; rd_pp1(pp, erow, ecp, c, hh);
        sumreg += sp + sigf(c) * (sigf(hh) - sp);
      }
      __syncthreads();
      wr_pp1(pp, acc[1], w, lane);        // s8
      __syncthreads();
      {
        float c, hh; rd_pp1(pp, erow, ecp, c, hh);
        sumreg += sp + sigf(c) * (fmaxf(hh, 0.f) - sp);
      }
      float hn = sumreg * 0.125f;
      __builtin_nontemporal_store(hn, &out[(size_t)t * 131072 + eo]);  // no L2 alloc
      if (t == 399)
        __builtin_nontemporal_store(hn, &out[(size_t)400 * 131072 + eo]);
      st_state(stg + 0 * SLOT_ELEMS, eo, hn, tid);
      sumreg = 0.f;
    }
    set_flag(flags, g, pt, base + 5);
  }
}

// ---------------- host launch ----------------------------------------------
extern "C" void kernel_launch(void* const* d_in, const int* in_sizes, int n_in,
                              void* d_out, int out_size, void* d_ws, size_t ws_size,
                              hipStream_t stream) {
  const float* x  = (const float*)d_in[0];
  const float* h0 = (const float*)d_in[1];
  const float* W0 = (const float*)d_in[2];
  const float* Ws = (const float*)d_in[3];
  float* out = (float*)d_out;
  char* ws = (char*)d_ws;

  (void)in_sizes; (void)n_in; (void)out_size; (void)ws_size;

  (void)hipMemsetAsync(ws + WS_BAR, 0, 16384, stream);
  hipLaunchKernelGGL(prep_kernel, dim3(2048), dim3(256), 0, stream, W0, Ws, h0, ws);

  void* args[3] = {(void*)&x, (void*)&out, (void*)&ws};
  (void)hipLaunchCooperativeKernel((void*)rnn_main, dim3(256), dim3(512), args, 0, stream);
}